// Round 1
// 435.976 us; speedup vs baseline: 1.0472x; 1.0472x over previous
//
#include <hip/hip_runtime.h>

// ---------- common ----------
typedef short bf16x8 __attribute__((ext_vector_type(8)));
typedef float f32x4  __attribute__((ext_vector_type(4)));

__device__ __forceinline__ unsigned short f2bf(float x) {
    unsigned int u = __float_as_uint(x);
    unsigned int r = (u + 0x7FFFu + ((u >> 16) & 1u)) >> 16;
    return (unsigned short)r;
}
__device__ __forceinline__ float bf2f(unsigned short b) {
    return __uint_as_float(((unsigned int)b) << 16);
}

typedef __attribute__((address_space(1))) const void* as1_cvp;
typedef __attribute__((address_space(3))) void* as3_vp;
__device__ __forceinline__ void cp16(const void* g, void* l) {
    // async global->LDS DMA, 16B per lane; LDS dst = wave-uniform base + lane*16
    __builtin_amdgcn_global_load_lds((as1_cvp)g, (as3_vp)l, 16, 0, 0);
}

#define P_TOT 6400          // B*N
#define NRH   16
#define NSEQ  100
#define GROWS 640000        // B*N*N

// ---------- kernel 1: cast a_features fp32 -> bf16 ----------
__global__ void k_cvt_a(const float* __restrict__ a, unsigned short* __restrict__ o, int n4) {
    int i = blockIdx.x * 256 + threadIdx.x;
    if (i < n4) {
        float4 v = ((const float4*)a)[i];
        ushort4 u;
        u.x = f2bf(v.x); u.y = f2bf(v.y); u.z = f2bf(v.z); u.w = f2bf(v.w);
        ((ushort4*)o)[i] = u;
    }
}

// ---------- kernel 2: transpose W[2048][1024] -> Wt rows n (z=0:K cols, z=1:Q cols) ----------
__global__ void k_tw(const float* __restrict__ Wk, const float* __restrict__ Wq,
                     unsigned short* __restrict__ Wt) {
    __shared__ float t[32][33];
    const float* W = blockIdx.z ? Wq : Wk;
    unsigned short* out = Wt + (size_t)blockIdx.z * 1024 * 2048;
    int n0 = blockIdx.x * 32, k0 = blockIdx.y * 32;
    int tx = threadIdx.x & 31, ty = threadIdx.x >> 5;   // 32 x 8
#pragma unroll
    for (int r = 0; r < 32; r += 8)
        t[ty + r][tx] = W[(size_t)(k0 + ty + r) * 1024 + n0 + tx];
    __syncthreads();
#pragma unroll
    for (int r = 0; r < 32; r += 8)
        out[(size_t)(n0 + ty + r) * 2048 + k0 + tx] = f2bf(t[tx][ty + r]);
}

// ---------- kernel 3: gate GEMM + log -> lg[h][b*N*N + i*N + j] bf16 ----------
// 4 lanes per row; wg stride 17 (q-groups land 16 banks apart -> 2-way, free).
__global__ void k_gate(const float* __restrict__ g, const float* __restrict__ Wg,
                       const float* __restrict__ bg, unsigned short* __restrict__ lg) {
    __shared__ float wg[64 * 17];
    __shared__ float bgs[16];
    int tid = threadIdx.x;
    if (tid < 16) bgs[tid] = bg[tid];
    for (int i = tid; i < 1024; i += 256) {
        int c = i >> 4, hh = i & 15;
        wg[c * 17 + hh] = Wg[i];
    }
    __syncthreads();

    int row = blockIdx.x * 64 + (tid >> 2);
    int q   = tid & 3;                       // quarter of the 64-dim input
    const float4* gp = (const float4*)(g + (size_t)row * 64 + q * 16);

    float acc[16];
#pragma unroll
    for (int h = 0; h < 16; h++) acc[h] = 0.f;
#pragma unroll
    for (int c4 = 0; c4 < 4; c4++) {
        float4 gv = gp[c4];
        int cb = q * 16 + c4 * 4;
#pragma unroll
        for (int h = 0; h < 16; h++) acc[h] += gv.x * wg[(cb + 0) * 17 + h];
#pragma unroll
        for (int h = 0; h < 16; h++) acc[h] += gv.y * wg[(cb + 1) * 17 + h];
#pragma unroll
        for (int h = 0; h < 16; h++) acc[h] += gv.z * wg[(cb + 2) * 17 + h];
#pragma unroll
        for (int h = 0; h < 16; h++) acc[h] += gv.w * wg[(cb + 3) * 17 + h];
    }
#pragma unroll
    for (int h = 0; h < 16; h++) {
        acc[h] += __shfl_xor(acc[h], 1);
        acc[h] += __shfl_xor(acc[h], 2);
    }
    // every lane holds full sums; lane q stores h = 4q..4q+3
#pragma unroll
    for (int u = 0; u < 4; u++) {
        int h = q * 4 + u;
        float v = fmaxf(acc[h] + bgs[h], 1e-6f);
        lg[(size_t)h * GROWS + row] = f2bf(__logf(v));
    }
}

// ---------- kernel 4: kq2[6400][2048] = A_bf[6400][2048] @ Wt^T + bias ----------
// 256x256 tile, BK=32, 4-slot circular LDS buffer, counted-vmcnt pipeline
// (stage tile t+3 while computing tile t; vmcnt(8) per tile, never 0 in loop),
// T2 XOR-swizzle on LDS (src-side pre-swizzle for global_load_lds + swizzled
// ds_read), T5 setprio around MFMA clusters, raw s_barrier (no __syncthreads
// -> no compiler vmcnt(0) drain).
__global__ __launch_bounds__(512, 2) void k_gemm(const unsigned short* __restrict__ A,
                                                 const unsigned short* __restrict__ Wt,
                                                 const float* __restrict__ bK,
                                                 const float* __restrict__ bQ,
                                                 unsigned short* __restrict__ out) {
    __shared__ unsigned short sm[65536];   // 4 slots x (A 8192 ush | B 8192 ush) = 128 KiB

    int lid = blockIdx.x;                  // 200 blocks
    int id  = (lid & 7) * 25 + (lid >> 3); // XCD-contiguous (200 % 8 == 0, bijective)
    int mb = id >> 3, nb = id & 7;         // 25 x 8 tiles
    int mBase = mb << 8, nBase = nb << 8;
    int tid = threadIdx.x, lane = tid & 63, w = tid >> 6;
    int wm = w >> 2, wn = w & 3;           // 2 x 4 waves, 128x64 out each
    int l15 = lane & 15, q = lane >> 4;

    // ---- staging sources: chunk tid (rows 0-127) and tid+512 (rows 128-255),
    //      source pre-swizzled so linear LDS + swizzled read = correct data ----
    int cs = tid ^ ((tid >> 3) & 3);       // swz: chunk ^= (chunk>>3)&3  (byte^=((L>>7)&3)<<4)
    int r0 = cs >> 2, cc = (cs & 3) << 3;  // row in [0,128), col elem
    const unsigned short* gA0 = A  + (size_t)(mBase + r0) * 2048 + cc;
    const unsigned short* gA1 = gA0 + (size_t)128 * 2048;
    const unsigned short* gB0 = Wt + (size_t)(nBase + r0) * 2048 + cc;
    const unsigned short* gB1 = gB0 + (size_t)128 * 2048;
    unsigned short* dA_base = sm + w * 512;   // + slot*16384 (ushorts); lane*16B is implicit

    // ---- swizzled frag read byte-offsets within a slot ----
    int offA[8], offB[4];
#pragma unroll
    for (int mt = 0; mt < 8; mt++) {
        int r = wm * 128 + mt * 16 + l15;
        int L = r * 64 + q * 16;
        offA[mt] = L ^ (((r >> 1) & 3) << 4);
    }
#pragma unroll
    for (int nt = 0; nt < 4; nt++) {
        int r = wn * 64 + nt * 16 + l15;
        int L = r * 64 + q * 16;
        offB[nt] = 16384 + (L ^ (((r >> 1) & 3) << 4));
    }

    f32x4 zero4 = {0.f, 0.f, 0.f, 0.f};
    f32x4 acc[8][4];
#pragma unroll
    for (int i = 0; i < 8; i++)
#pragma unroll
        for (int j = 0; j < 4; j++) acc[i][j] = zero4;

    // ---- prologue: stage tiles 0..2 into slots 0..2 (order A0,B0,A1,B1 per tile) ----
#pragma unroll
    for (int t = 0; t < 3; t++) {
        unsigned short* dA = dA_base + t * 16384;
        int ko = t * 32;
        cp16(gA0 + ko, dA);
        cp16(gB0 + ko, dA + 8192);
        cp16(gA1 + ko, dA + 4096);
        cp16(gB1 + ko, dA + 12288);
    }
    asm volatile("s_waitcnt vmcnt(8)" ::: "memory");   // tile 0 landed
    __builtin_amdgcn_s_barrier();

    // ---- main loop: 64 K-tiles, 2 phases each, stage t+3 ----
#pragma unroll 1
    for (int t = 0; t < 64; t++) {
        const char* sb = (const char*)sm + (t & 3) * 32768;
        unsigned short* dA = dA_base + ((t + 3) & 3) * 16384;
        int ko = ((t + 3) & 63) * 32;      // wrap: junk into never-read slots at tail

        // ---- phase 0: B all + A rows 0-63 of wave ----
        bf16x8 bF[4], aF[4];
#pragma unroll
        for (int nt = 0; nt < 4; nt++) bF[nt] = *(const bf16x8*)(sb + offB[nt]);
#pragma unroll
        for (int mt = 0; mt < 4; mt++) aF[mt] = *(const bf16x8*)(sb + offA[mt]);
        cp16(gA0 + ko, dA);
        cp16(gB0 + ko, dA + 8192);
        asm volatile("s_waitcnt lgkmcnt(0)" ::: "memory");  // drain own ds_reads pre-barrier
        __builtin_amdgcn_s_barrier();
        __builtin_amdgcn_s_setprio(1);
#pragma unroll
        for (int mt = 0; mt < 4; mt++)
#pragma unroll
            for (int nt = 0; nt < 4; nt++)
                acc[mt][nt] = __builtin_amdgcn_mfma_f32_16x16x32_bf16(aF[mt], bF[nt], acc[mt][nt], 0, 0, 0);
        __builtin_amdgcn_s_setprio(0);

        // ---- phase 1: A rows 64-127 of wave, reuse bF ----
        bf16x8 aG[4];
#pragma unroll
        for (int mt = 0; mt < 4; mt++) aG[mt] = *(const bf16x8*)(sb + offA[4 + mt]);
        cp16(gA1 + ko, dA + 4096);
        cp16(gB1 + ko, dA + 12288);
        asm volatile("s_waitcnt vmcnt(8)" ::: "memory");    // next tile landed; 2 tiles stay in flight
        asm volatile("s_waitcnt lgkmcnt(0)" ::: "memory");
        __builtin_amdgcn_s_barrier();
        __builtin_amdgcn_s_setprio(1);
#pragma unroll
        for (int mt = 0; mt < 4; mt++)
#pragma unroll
            for (int nt = 0; nt < 4; nt++)
                acc[4 + mt][nt] = __builtin_amdgcn_mfma_f32_16x16x32_bf16(aG[mt], bF[nt], acc[4 + mt][nt], 0, 0, 0);
        __builtin_amdgcn_s_setprio(0);
    }
    asm volatile("s_waitcnt vmcnt(0)" ::: "memory");  // drain junk stages before endpgm

    // ---- epilogue ----
#pragma unroll
    for (int nt = 0; nt < 4; nt++) {
        int n = nBase + wn * 64 + nt * 16 + l15;
        float bv = (n < 1024) ? bK[n] : bQ[n - 1024];
#pragma unroll
        for (int mt = 0; mt < 8; mt++)
#pragma unroll
            for (int r = 0; r < 4; r++) {
                int m = mBase + wm * 128 + mt * 16 + q * 4 + r;
                out[(size_t)m * 2048 + n] = f2bf(acc[mt][nt][r] + bv);
            }
    }
}

// ---------- kernel 5: fused attention per (b,h) ----------
// Transposed score matrix: Sm[j][i] = q_j.k_i/8 -> row softmax (contiguous),
// fin lands natively in PV A-operand layout. V staged to LDS coalesced.
__global__ __launch_bounds__(256) void k_attn(const unsigned short* __restrict__ kq,
                                              const unsigned short* __restrict__ abf,
                                              const unsigned short* __restrict__ lg,
                                              const float* __restrict__ wsp,
                                              const float* __restrict__ bsp,
                                              float* __restrict__ out) {
    __shared__ unsigned short shA[112 * 72 * 2];   // Ks|Qs, later fT[112][136]
    __shared__ unsigned short shB[128 * 128];      // Sm[112][102], later Vs[128][128]
    __shared__ float inv[112];
    unsigned short* Ks = shA;
    unsigned short* Qs = shA + 112 * 72;
    unsigned short* fT = shA;
    unsigned short* Sm = shB;
    unsigned short* Vs = shB;

    int h = blockIdx.x, b = blockIdx.y;
    int tid = threadIdx.x, lane = tid & 63, w = tid >> 6;
    int l15 = lane & 15, q = lane >> 4;

    // ---- stage K,Q (rows >= 100 zeroed) ----
    const unsigned short* Kg = kq + (size_t)(b * NSEQ) * 2048 + h * 64;
    const unsigned short* Qg = Kg + 1024;
    for (int c = tid; c < 112 * 8; c += 256) {
        int row = c >> 3, off = (c & 7) * 8;
        uint4 kv = {0, 0, 0, 0}, qv = {0, 0, 0, 0};
        if (row < NSEQ) {
            kv = *(const uint4*)(Kg + (size_t)row * 2048 + off);
            qv = *(const uint4*)(Qg + (size_t)row * 2048 + off);
        }
        *(uint4*)(&Ks[row * 72 + off]) = kv;
        *(uint4*)(&Qs[row * 72 + off]) = qv;
    }
    __syncthreads();

    // ---- Sm[j][i] = q_j . k_i / 8  (A=Q, B=K) ----
    for (int p = w; p < 49; p += 4) {
        int mt = p / 7, nt = p % 7;
        bf16x8 a0 = *(const bf16x8*)(&Qs[(mt * 16 + l15) * 72 + q * 8]);
        bf16x8 a1 = *(const bf16x8*)(&Qs[(mt * 16 + l15) * 72 + 32 + q * 8]);
        bf16x8 b0 = *(const bf16x8*)(&Ks[(nt * 16 + l15) * 72 + q * 8]);
        bf16x8 b1 = *(const bf16x8*)(&Ks[(nt * 16 + l15) * 72 + 32 + q * 8]);
        f32x4 c = {0.f, 0.f, 0.f, 0.f};
        c = __builtin_amdgcn_mfma_f32_16x16x32_bf16(a0, b0, c, 0, 0, 0);
        c = __builtin_amdgcn_mfma_f32_16x16x32_bf16(a1, b1, c, 0, 0, 0);
        int i = nt * 16 + l15;
        if (i < NSEQ) {
#pragma unroll
            for (int r = 0; r < 4; r++) {
                int j = mt * 16 + q * 4 + r;
                Sm[j * 102 + i] = f2bf(c[r] * 0.125f);
            }
        }
    }
    __syncthreads();

    // ---- row softmax over i, gate added from global (coalesced across threads) ----
    if (tid < 112) {
        int j = tid;
        unsigned short* Frow = fT + j * 136;
        if (j < NSEQ) {
            const unsigned short* Srow = Sm + j * 102;
            const unsigned short* lgc = lg + (size_t)h * GROWS + b * 10000 + j;
            float mx = -1e30f;
            for (int i = 0; i < NSEQ; i++) {
                float v = bf2f(Srow[i]) + bf2f(lgc[i * 100]);
                Frow[i] = f2bf(v);
                mx = fmaxf(mx, v);
            }
            float sum = 0.f;
            for (int i = 0; i < NSEQ; i++) {
                float e = __expf(bf2f(Frow[i]) - mx);
                sum += e;
                Frow[i] = f2bf(e);
            }
            for (int i = NSEQ; i < 128; i++) Frow[i] = 0;
            inv[j] = 1.f / sum;
        } else {
            for (int i = 0; i < 128; i++) Frow[i] = 0;
            inv[j] = 0.f;
        }
    }
    __syncthreads();

    // ---- stage V (overwrites Sm; rows >= 100 zeroed) ----
    const unsigned short* Vg = abf + (size_t)(b * NSEQ) * 2048 + h * 128;
    for (int c = tid; c < 128 * 16; c += 256) {
        int row = c >> 4, off = (c & 15) * 8;
        uint4 v = {0, 0, 0, 0};
        if (row < NSEQ) v = *(const uint4*)(Vg + (size_t)row * 2048 + off);
        *(uint4*)(&Vs[row * 128 + off]) = v;
    }
    __syncthreads();

    // ---- R = fin^T @ V; epilogue folds 1/sum, w_s, b_s ----
    float wsv = wsp[0], bsv = bsp[0];
    for (int nt2 = 0; nt2 < 2; nt2++) {
        int d0 = (w * 2 + nt2) * 16;
        bf16x8 bF[4];
#pragma unroll
        for (int ks = 0; ks < 4; ks++) {
            bf16x8 f;
#pragma unroll
            for (int jj = 0; jj < 8; jj++)
                f[jj] = (short)Vs[(ks * 32 + q * 8 + jj) * 128 + d0 + l15];
            bF[ks] = f;
        }
        for (int mt = 0; mt < 7; mt++) {
            f32x4 c = {0.f, 0.f, 0.f, 0.f};
#pragma unroll
            for (int ks = 0; ks < 4; ks++) {
                bf16x8 aF = *(const bf16x8*)(&fT[(mt * 16 + l15) * 136 + ks * 32 + q * 8]);
                c = __builtin_amdgcn_mfma_f32_16x16x32_bf16(aF, bF[ks], c, 0, 0, 0);
            }
#pragma unroll
            for (int r = 0; r < 4; r++) {
                int j = mt * 16 + q * 4 + r;
                if (j < NSEQ)
                    out[(size_t)(b * NSEQ + j) * 2048 + h * 128 + d0 + l15] = c[r] * inv[j] * wsv + bsv;
            }
        }
    }
}

// ---------- launch ----------
extern "C" void kernel_launch(void* const* d_in, const int* in_sizes, int n_in,
                              void* d_out, int out_size, void* d_ws, size_t ws_size,
                              hipStream_t stream) {
    const float* a  = (const float*)d_in[0];
    const float* g  = (const float*)d_in[1];
    const float* Wg = (const float*)d_in[4];
    const float* bg = (const float*)d_in[5];
    const float* WK = (const float*)d_in[6];
    const float* bK = (const float*)d_in[7];
    const float* WQ = (const float*)d_in[8];
    const float* bQ = (const float*)d_in[9];
    const float* ws_s = (const float*)d_in[10];
    const float* bs_s = (const float*)d_in[11];
    float* out = (float*)d_out;

    // workspace layout (bytes)
    const size_t off_abf = 0;                        // 6400*2048*2  = 26,214,400
    const size_t off_wt  = off_abf + 26214400;       // 2048*2048*2  =  8,388,608
    const size_t off_kq  = off_wt + 8388608;         // 6400*2048*2  = 26,214,400
    const size_t off_lg  = off_kq + 26214400;        // 16*640000*2  = 20,480,000
    const size_t need    = off_lg + 20480000;
    if (ws_size < need) return;

    char* ws = (char*)d_ws;
    unsigned short* a_bf = (unsigned short*)(ws + off_abf);
    unsigned short* Wt   = (unsigned short*)(ws + off_wt);
    unsigned short* kq   = (unsigned short*)(ws + off_kq);
    unsigned short* lg   = (unsigned short*)(ws + off_lg);

    k_cvt_a<<<12800, 256, 0, stream>>>(a, a_bf, 3276800);
    k_tw<<<dim3(32, 64, 2), 256, 0, stream>>>(WK, WQ, Wt);
    k_gate<<<10000, 256, 0, stream>>>(g, Wg, bg, lg);
    k_gemm<<<200, 512, 0, stream>>>(a_bf, Wt, bK, bQ, kq);
    k_attn<<<dim3(16, 64), 256, 0, stream>>>(kq, a_bf, lg, ws_s, bs_s, out);
}